// Round 6
// baseline (11675.489 us; speedup 1.0000x reference)
//
#include <hip/hip_runtime.h>
#include <math.h>

#define I_SZ 1024
#define H_SZ 1024
#define FH   4096
#define B_SZ 64
#define T_SZ 512
#define NWG  128
#define NTHR 512

typedef _Float16 half8 __attribute__((ext_vector_type(8)));
typedef float    f32x4 __attribute__((ext_vector_type(4)));

#define MiB (1u << 20)
#define SLOT_HALFS 65536  // 64 x 1024 fp16 h = 128 KiB per slot

// ---- ws layout (max byte = 288 MiB) ----
// [0,1K)     ctrl (unused counter slot)
// [1K,2K)    flags[128] barrier flag array
// [4K,+256K) h fp16 double buffer (2 slots)
// [1M,9M)    WhT fp16 [4096][1024]
// [16M,24M)  WiT fp16 [4096][1024]
// [32M,288M) G' fp16, permuted: [(t*128+wg)*64 + b][32]  (4 KiB/WG/step, contiguous)

// Transpose+convert W[1024][4096] fp32 -> WT[4096][1024] fp16.
__global__ __launch_bounds__(256) void k_cvt_wT(const float* __restrict__ W,
                                                _Float16* __restrict__ WT) {
  int tid = blockIdx.x * 256 + threadIdx.x;
  int n  = tid & (FH - 1);
  int k8 = tid >> 12;
  half8 h;
#pragma unroll
  for (int j = 0; j < 8; j++) h[j] = (_Float16)W[(size_t)(k8 * 8 + j) * FH + n];
  *(half8*)(WT + (size_t)n * 1024 + k8 * 8) = h;
}

// G'[(t*128+w)*64+b][g*8+j] = x[b][t][:] @ Wi[:][col] + bi + bh, fp16.
// col = g*1024 + w*8 + j. Per-(WG,step) slice is 4 KiB CONTIGUOUS.
__global__ __launch_bounds__(256) void k_gemm_pre(
    const float* __restrict__ x, const _Float16* __restrict__ WiT,
    const float* __restrict__ bi, const float* __restrict__ bh,
    _Float16* __restrict__ G) {
  __shared__ _Float16 As[128][40];
  __shared__ _Float16 Bs[128][40];
  const int tn = blockIdx.x, tm = blockIdx.y;
  const int tx = threadIdx.x;
  const int l = tx & 63, wv = tx >> 6;
  const int wm = wv & 1, wn = wv >> 1;
  const int r0 = tx >> 2, q0 = tx & 3;
  const int m0 = tm * 128 + r0, m1 = m0 + 64;
  const float* aR0 = x + (size_t)((m0 & 63) * T_SZ + (m0 >> 6)) * I_SZ + q0 * 8;
  const float* aR1 = x + (size_t)((m1 & 63) * T_SZ + (m1 >> 6)) * I_SZ + q0 * 8;
  const _Float16* bR0 = WiT + (size_t)(tn * 128 + r0) * 1024 + q0 * 8;
  const _Float16* bR1 = WiT + (size_t)(tn * 128 + 64 + r0) * 1024 + q0 * 8;

  f32x4 acc[4][4];
#pragma unroll
  for (int a = 0; a < 4; a++)
#pragma unroll
    for (int b = 0; b < 4; b++) acc[a][b] = {0.f, 0.f, 0.f, 0.f};

  for (int kt = 0; kt < 32; kt++) {
    __syncthreads();
    float4 va0 = *(const float4*)(aR0 + kt * 32);
    float4 va1 = *(const float4*)(aR0 + kt * 32 + 4);
    float4 vb0 = *(const float4*)(aR1 + kt * 32);
    float4 vb1 = *(const float4*)(aR1 + kt * 32 + 4);
    half8 ha, hb;
    ha[0] = (_Float16)va0.x; ha[1] = (_Float16)va0.y; ha[2] = (_Float16)va0.z; ha[3] = (_Float16)va0.w;
    ha[4] = (_Float16)va1.x; ha[5] = (_Float16)va1.y; ha[6] = (_Float16)va1.z; ha[7] = (_Float16)va1.w;
    hb[0] = (_Float16)vb0.x; hb[1] = (_Float16)vb0.y; hb[2] = (_Float16)vb0.z; hb[3] = (_Float16)vb0.w;
    hb[4] = (_Float16)vb1.x; hb[5] = (_Float16)vb1.y; hb[6] = (_Float16)vb1.z; hb[7] = (_Float16)vb1.w;
    *(half8*)(&As[r0][q0 * 8])      = ha;
    *(half8*)(&As[64 + r0][q0 * 8]) = hb;
    *(half8*)(&Bs[r0][q0 * 8])      = *(const half8*)(bR0 + kt * 32);
    *(half8*)(&Bs[64 + r0][q0 * 8]) = *(const half8*)(bR1 + kt * 32);
    __syncthreads();
    half8 af[4], bf[4];
#pragma unroll
    for (int i = 0; i < 4; i++) {
      af[i] = *(const half8*)(&As[wm * 64 + i * 16 + (l & 15)][(l >> 4) * 8]);
      bf[i] = *(const half8*)(&Bs[wn * 64 + i * 16 + (l & 15)][(l >> 4) * 8]);
    }
#pragma unroll
    for (int i = 0; i < 4; i++)
#pragma unroll
      for (int j2 = 0; j2 < 4; j2++)
        acc[i][j2] = __builtin_amdgcn_mfma_f32_16x16x32_f16(af[i], bf[j2], acc[i][j2], 0, 0, 0);
  }
#pragma unroll
  for (int j2 = 0; j2 < 4; j2++) {
    const int col = tn * 128 + wn * 64 + j2 * 16 + (l & 15);
    const float bias = bi[col] + bh[col];
    const int g = col >> 10;                 // gate block
    const int w = (col & 1023) >> 3;         // owning WG
    const int j = col & 7;                   // col within WG slice
#pragma unroll
    for (int i = 0; i < 4; i++) {
      const int mb = tm * 128 + wm * 64 + i * 16 + ((l >> 4) << 2);
#pragma unroll
      for (int r = 0; r < 4; r++) {
        const int row = mb + r;
        const int t = row >> 6, b = row & 63;
        G[(((size_t)t * 128 + w) * 64 + b) * 32 + g * 8 + j] =
            (_Float16)(acc[i][j2][r] + bias);
      }
    }
  }
}

// Persistent recurrent kernel: 128 WGs x 512 thr (8 waves); WG owns h cols
// [8wg, 8wg+8). h exchange: fp16 2-slot dbuf; WRITES via proven sc0/sc1 8B
// system-scope stores (write-through to LLC); READS via PLAIN CACHED
// coalesced dwordx4 loads, made correct by a device-scope ACQUIRE fence
// (buffer_inv sc1: invalidates this XCD's L2) issued after the grid barrier
// and before staging. 8 WGs/XCD then share h lines in L2. Wh frags via
// rolling register prefetch; G' slice is 4 KiB contiguous per WG per step.
// Grid sync: flag barrier (128 flags, 8B UC polls -- unaffected by L2 inv).
__global__ __launch_bounds__(NTHR, 1) void k_lstm(
    const _Float16* __restrict__ WhT, const _Float16* __restrict__ G,
    _Float16* __restrict__ hdb, float* __restrict__ out, int* ctrl) {
  __shared__ _Float16 hstage[B_SZ * H_SZ];   // 128 KiB, XOR-swizzled rows
  __shared__ float gates[B_SZ][37];          // padded: 37%32=5, gcd(5,32)=1

  const int wg = blockIdx.x;
  const int jb = wg * 8;                     // first of 8 owned h-cols
  const int tx = threadIdx.x;
  const int l = tx & 63, wv = tx >> 6;
  const int wm = wv & 3;                     // batch quarter (16 rows)
  const int wn = wv >> 2;                    // gate-col half (16 cols)
  const int cc = l & 15;
  const int crow = 16 * wm + cc;             // A-frag batch row
  const int cB = 16 * wn + cc;               // C col in [0,32)
  const int gcol = (cB >> 3) * 1024 + jb + (cB & 7);  // WhT row
  const int kb = (l >> 4) * 8;               // frag k offset (halfs)
  const int cb = tx >> 1;                    // cell thread: batch row (tx<128)
  const int cq = (tx & 1) * 4;               // cell thread: first of 4 cols

  int* flags = ctrl + 256;                   // flags[128] at ws+1024
  const half8* bp = (const half8*)(WhT + (size_t)gcol * 1024 + kb);

  float cst[4] = {0.f, 0.f, 0.f, 0.f};
  float hl[4]  = {0.f, 0.f, 0.f, 0.f};

  for (int t = 0; t < T_SZ; t++) {
    if (t > 0) {
      // ---- ACQUIRE: invalidate this XCD's L2 so plain loads see the
      // sc0/sc1-written h (and fresh flag-era data). ----
      __builtin_amdgcn_fence(__ATOMIC_ACQUIRE, "agent");
    }

    // G prefetch: contiguous 4 KiB WG slice, plain cached, coalesced.
    unsigned long long gv[4] = {0, 0, 0, 0};
    if (tx < 128) {
      const _Float16* Gt = G + (((size_t)t * 128 + wg) * 64) * 32;
#pragma unroll
      for (int g4 = 0; g4 < 4; g4++)
        gv[g4] = *(const unsigned long long*)(Gt + cb * 32 + g4 * 8 + cq);
    }

    if (t > 0) {
      // ---- stage h_{t-1} into LDS: plain cached dwordx4, coalesced ----
      const _Float16* hb = hdb + (size_t)(t & 1) * SLOT_HALFS;
      const f32x4* hb16 = (const f32x4*)hb;
      f32x4 d[16];
#pragma unroll
      for (int i = 0; i < 16; i++) d[i] = hb16[i * NTHR + tx];
#pragma unroll
      for (int i = 0; i < 16; i++) {
        const int c = i * NTHR + tx;         // 16B chunk id
        const int r_ = c >> 7;               // LDS row (128 chunks/row)
        const int b_ = r_ * 2048 + (((c & 127) << 4) ^ ((r_ & 7) << 4));
        *(f32x4*)((char*)hstage + b_) = d[i];
      }
    }
    __syncthreads();  // sync1: hstage ready

    if (t > 0) {
      // ---- MFMA: C[16 batch][16 gatecol] = h @ WhT-slice, K=1024 ----
      f32x4 acc = {0.f, 0.f, 0.f, 0.f};
      const char* hsb = (const char*)hstage;
      const int rbase = crow * 2048;
      const int sw = (crow & 7) << 4;
      half8 bf[16];
#pragma unroll
      for (int p = 0; p < 16; p++) bf[p] = bp[p * 4];
#pragma unroll
      for (int ki = 0; ki < 32; ki++) {
        half8 b = bf[ki & 15];
        half8 af = *(const half8*)(hsb + rbase + ((ki * 64 + ((l >> 4) << 4)) ^ sw));
        if (ki < 16) bf[ki & 15] = bp[(ki + 16) * 4];
        acc = __builtin_amdgcn_mfma_f32_16x16x32_f16(af, b, acc, 0, 0, 0);
      }
#pragma unroll
      for (int r = 0; r < 4; r++)
        gates[16 * wm + ((l >> 4) << 2) + r][cB] = acc[r];
    } else {
      for (int i = tx; i < B_SZ * 37; i += NTHR) ((float*)gates)[i] = 0.f;
    }
    __syncthreads();  // sync2: gates ready

    if (tx < 128) {
      float hv[4];
#pragma unroll
      for (int j = 0; j < 4; j++) {
        const int jj = cq + j;
        union { unsigned long long u; _Float16 h[4]; } u0g, u1g, u2g, u3g;
        u0g.u = gv[0]; u1g.u = gv[1]; u2g.u = gv[2]; u3g.u = gv[3];
        float gi = gates[cb][ 0 + jj] + (float)u0g.h[j];
        float gf = gates[cb][ 8 + jj] + (float)u1g.h[j];
        float gg = gates[cb][16 + jj] + (float)u2g.h[j];
        float go = gates[cb][24 + jj] + (float)u3g.h[j];
        float ig = 1.f / (1.f + expf(-gi));
        float fg = 1.f / (1.f + expf(-gf));
        float gvv = tanhf(gg);
        float og = 1.f / (1.f + expf(-go));
        cst[j] = fg * cst[j] + ig * gvv;
        hv[j] = og * tanhf(cst[j]);
        hl[j] = hv[j];
      }
      *(float4*)(out + (size_t)t * (B_SZ * H_SZ) + (size_t)cb * H_SZ + jb + cq) =
          make_float4(hv[0], hv[1], hv[2], hv[3]);
      union { _Float16 h[4]; unsigned long long u; } pk;
#pragma unroll
      for (int j = 0; j < 4; j++) pk.h[j] = (_Float16)hv[j];
      _Float16* hn = hdb + (size_t)((t & 1) ^ 1) * SLOT_HALFS;
      __hip_atomic_store((unsigned long long*)(hn + (size_t)cb * H_SZ + jb + cq),
                         pk.u, __ATOMIC_RELAXED, __HIP_MEMORY_SCOPE_SYSTEM);
    }

    if (t + 1 < T_SZ) {
      // ---- flag barrier: report (distinct addresses), then all-poll ----
      asm volatile("s_waitcnt vmcnt(0)" ::: "memory");  // h stores at LLC
      __syncthreads();                                   // sync3
      if (tx == 0)
        __hip_atomic_store(flags + wg, t + 1, __ATOMIC_RELAXED,
                           __HIP_MEMORY_SCOPE_SYSTEM);
      if (wv == 0) {
        const int target = t + 1;
        const unsigned long long* fp = (const unsigned long long*)flags;
        int guard = 0;
        for (;;) {
          unsigned long long f0 = __hip_atomic_load(fp + l, __ATOMIC_RELAXED,
                                                    __HIP_MEMORY_SCOPE_SYSTEM);
          bool ok = ((int)(f0 & 0xffffffffu) >= target) &&
                    ((int)(f0 >> 32) >= target);
          if (__all(ok)) break;
          if (++guard > (1 << 20)) break;  // deadlock -> fast wrong answer
          __builtin_amdgcn_s_sleep(4);
        }
      }
      __syncthreads();  // sync4
    }
  }

  if (tx < 128) {
    const size_t ob = (size_t)T_SZ * (B_SZ * H_SZ);
    *(float4*)(out + ob + (size_t)cb * H_SZ + jb + cq) =
        make_float4(hl[0], hl[1], hl[2], hl[3]);
    *(float4*)(out + ob + B_SZ * H_SZ + (size_t)cb * H_SZ + jb + cq) =
        make_float4(cst[0], cst[1], cst[2], cst[3]);
  }
}

extern "C" void kernel_launch(void* const* d_in, const int* in_sizes, int n_in,
                              void* d_out, int out_size, void* d_ws, size_t ws_size,
                              hipStream_t stream) {
  (void)in_sizes; (void)n_in; (void)out_size; (void)ws_size;
  const float* x  = (const float*)d_in[0];
  const float* Wi = (const float*)d_in[1];
  const float* Wh = (const float*)d_in[2];
  const float* bi = (const float*)d_in[3];
  const float* bh = (const float*)d_in[4];
  float* out = (float*)d_out;
  char* ws = (char*)d_ws;

  int* ctrl     = (int*)ws;
  _Float16* hdb = (_Float16*)(ws + 4096);
  _Float16* WhT = (_Float16*)(ws + (size_t)1 * MiB);
  _Float16* WiT = (_Float16*)(ws + (size_t)16 * MiB);
  _Float16* G   = (_Float16*)(ws + (size_t)32 * MiB);

  (void)hipMemsetAsync(ws, 0, 4096, stream);
  k_cvt_wT<<<2048, 256, 0, stream>>>(Wi, WiT);
  k_cvt_wT<<<2048, 256, 0, stream>>>(Wh, WhT);
  dim3 g2(32, 256);
  k_gemm_pre<<<g2, 256, 0, stream>>>(x, WiT, bi, bh, G);
  k_lstm<<<NWG, NTHR, 0, stream>>>(WhT, G, hdb, out, ctrl);
}

// Round 7
// 6796.580 us; speedup vs baseline: 1.7178x; 1.7178x over previous
//
#include <hip/hip_runtime.h>
#include <math.h>

#define I_SZ 1024
#define H_SZ 1024
#define FH   4096
#define B_SZ 64
#define T_SZ 512
#define NWG  128
#define NTHR 256

typedef _Float16 half8 __attribute__((ext_vector_type(8)));
typedef float    f32x4 __attribute__((ext_vector_type(4)));

#define MiB (1u << 20)

// ---- ws layout (max byte = 288 MiB) ----
// [0,1K)     ctrl (unused)
// [1K,2K)    flags: group g's 32 flags at ints [g*64, g*64+32)
// [1M,9M)    WhT fp16 [4096][1024]
// [16M,24M)  WiT fp16 [4096][1024]
// [32M,288M) G' fp16: [((t*4+group)*32+w)*16 + r][128]  (4 KiB per WG-step, contiguous)
// h exchange rides on `out` (fp32, write-once) -> plain cached reads, no fence.

// Transpose+convert W[1024][4096] fp32 -> WT[4096][1024] fp16.
__global__ __launch_bounds__(256) void k_cvt_wT(const float* __restrict__ W,
                                                _Float16* __restrict__ WT) {
  int tid = blockIdx.x * 256 + threadIdx.x;
  int n  = tid & (FH - 1);
  int k8 = tid >> 12;
  half8 h;
#pragma unroll
  for (int j = 0; j < 8; j++) h[j] = (_Float16)W[(size_t)(k8 * 8 + j) * FH + n];
  *(half8*)(WT + (size_t)n * 1024 + k8 * 8) = h;
}

// G'[(t,group,w)][r][gate*32+j] = x[b][t][:] @ Wi[:][col] + bi + bh, fp16.
// col = gate*1024 + w*32 + j ; b = group*16 + r.
__global__ __launch_bounds__(256) void k_gemm_pre(
    const float* __restrict__ x, const _Float16* __restrict__ WiT,
    const float* __restrict__ bi, const float* __restrict__ bh,
    _Float16* __restrict__ G) {
  __shared__ _Float16 As[128][40];
  __shared__ _Float16 Bs[128][40];
  const int tn = blockIdx.x, tm = blockIdx.y;
  const int tx = threadIdx.x;
  const int l = tx & 63, wv = tx >> 6;
  const int wm = wv & 1, wn = wv >> 1;
  const int r0 = tx >> 2, q0 = tx & 3;
  const int m0 = tm * 128 + r0, m1 = m0 + 64;
  const float* aR0 = x + (size_t)((m0 & 63) * T_SZ + (m0 >> 6)) * I_SZ + q0 * 8;
  const float* aR1 = x + (size_t)((m1 & 63) * T_SZ + (m1 >> 6)) * I_SZ + q0 * 8;
  const _Float16* bR0 = WiT + (size_t)(tn * 128 + r0) * 1024 + q0 * 8;
  const _Float16* bR1 = WiT + (size_t)(tn * 128 + 64 + r0) * 1024 + q0 * 8;

  f32x4 acc[4][4];
#pragma unroll
  for (int a = 0; a < 4; a++)
#pragma unroll
    for (int b = 0; b < 4; b++) acc[a][b] = {0.f, 0.f, 0.f, 0.f};

  for (int kt = 0; kt < 32; kt++) {
    __syncthreads();
    float4 va0 = *(const float4*)(aR0 + kt * 32);
    float4 va1 = *(const float4*)(aR0 + kt * 32 + 4);
    float4 vb0 = *(const float4*)(aR1 + kt * 32);
    float4 vb1 = *(const float4*)(aR1 + kt * 32 + 4);
    half8 ha, hb;
    ha[0] = (_Float16)va0.x; ha[1] = (_Float16)va0.y; ha[2] = (_Float16)va0.z; ha[3] = (_Float16)va0.w;
    ha[4] = (_Float16)va1.x; ha[5] = (_Float16)va1.y; ha[6] = (_Float16)va1.z; ha[7] = (_Float16)va1.w;
    hb[0] = (_Float16)vb0.x; hb[1] = (_Float16)vb0.y; hb[2] = (_Float16)vb0.z; hb[3] = (_Float16)vb0.w;
    hb[4] = (_Float16)vb1.x; hb[5] = (_Float16)vb1.y; hb[6] = (_Float16)vb1.z; hb[7] = (_Float16)vb1.w;
    *(half8*)(&As[r0][q0 * 8])      = ha;
    *(half8*)(&As[64 + r0][q0 * 8]) = hb;
    *(half8*)(&Bs[r0][q0 * 8])      = *(const half8*)(bR0 + kt * 32);
    *(half8*)(&Bs[64 + r0][q0 * 8]) = *(const half8*)(bR1 + kt * 32);
    __syncthreads();
    half8 af[4], bf[4];
#pragma unroll
    for (int i = 0; i < 4; i++) {
      af[i] = *(const half8*)(&As[wm * 64 + i * 16 + (l & 15)][(l >> 4) * 8]);
      bf[i] = *(const half8*)(&Bs[wn * 64 + i * 16 + (l & 15)][(l >> 4) * 8]);
    }
#pragma unroll
    for (int i = 0; i < 4; i++)
#pragma unroll
      for (int j2 = 0; j2 < 4; j2++)
        acc[i][j2] = __builtin_amdgcn_mfma_f32_16x16x32_f16(af[i], bf[j2], acc[i][j2], 0, 0, 0);
  }
#pragma unroll
  for (int j2 = 0; j2 < 4; j2++) {
    const int col = tn * 128 + wn * 64 + j2 * 16 + (l & 15);
    const float bias = bi[col] + bh[col];
    const int gg = col >> 10;                // gate
    const int cg = col & 1023;
    const int w  = cg >> 5;                  // owning WG within group
    const int j  = cg & 31;                  // col within WG slice
#pragma unroll
    for (int i = 0; i < 4; i++) {
      const int mb = tm * 128 + wm * 64 + i * 16 + ((l >> 4) << 2);
#pragma unroll
      for (int r = 0; r < 4; r++) {
        const int row = mb + r;
        const int t = row >> 6, b = row & 63;
        G[((((size_t)t * 4 + (b >> 4)) * 32 + w) * 16 + (b & 15)) * 128 + gg * 32 + j] =
            (_Float16)(acc[i][j2][r] + bias);
      }
    }
  }
}

// Persistent recurrent kernel, BATCH-GROUPED: 4 groups x 16 batch rows;
// 32 WGs per group; WG (group,w) computes cols [w*32,w*32+32) of h for its
// group's 16 rows. All h exchange + sync is GROUP-LOCAL (32 WGs, 64 KB).
// h_{t-1} read from out[t-1] (write-once fp32 -> plain cached loads, L2
// dedup, no fence); h_t written via proven sc0/sc1 8B system-scope stores.
// Wave g of each WG owns gate g: C[16][32] = 2 MFMA tiles, K=1024, with
// rolling Wh-fragment prefetch (Wh slices stay L2-resident).
__global__ __launch_bounds__(NTHR, 1) void k_lstm(
    const _Float16* __restrict__ WhT, const _Float16* __restrict__ G,
    float* out, int* ctrl) {
  __shared__ _Float16 hstage[16 * 1024];     // 32 KiB, XOR-swizzled rows
  __shared__ float gates[4][16][36];         // 9 KiB, padded

  const int wg = blockIdx.x;
  const int group = wg >> 5, w = wg & 31;
  const int jb = w * 32;                     // first owned h-col
  const int tx = threadIdx.x;
  const int l = tx & 63, g = tx >> 6;        // wave index == gate index
  const int cc = l & 15;                     // MFMA A row / C col
  const int kb2 = (l >> 4) * 16;             // frag k offset in BYTES

  int* flags = ctrl + 256;                   // group g flags at [g*64, g*64+32)

  const half8* bq0 = (const half8*)(WhT + (size_t)(g * 1024 + jb + cc) * 1024 + (l >> 4) * 8);
  const half8* bq1 = (const half8*)((const _Float16*)bq0 + (size_t)16 * 1024);

  float cst[4] = {0.f, 0.f, 0.f, 0.f};
  float hl[4]  = {0.f, 0.f, 0.f, 0.f};

  for (int t = 0; t < T_SZ; t++) {
    // ---- G prefetch: 4 KiB contiguous block for (t, group, w) ----
    unsigned long long gv[4] = {0, 0, 0, 0};
    const _Float16* Gt = G + ((((size_t)t * 4 + group) * 32 + w) * 16) * 128;
    if (tx < 128) {
      const int rr = tx >> 3, jq = (tx & 7) * 4;
#pragma unroll
      for (int g4 = 0; g4 < 4; g4++)
        gv[g4] = *(const unsigned long long*)(Gt + rr * 128 + g4 * 32 + jq);
    }

    if (t > 0) {
      // ---- stage group's h_{t-1} (16x1024 fp32 from out) into fp16 LDS ----
      const float* hsrc = out + (size_t)(t - 1) * (B_SZ * H_SZ) + (size_t)(group * 16) * H_SZ;
#pragma unroll
      for (int bb = 0; bb < 2; bb++) {
        float4 d[8];
#pragma unroll
        for (int i = 0; i < 8; i++) {
          const int f = (bb * 8 + i) * NTHR + tx;
          d[i] = *(const float4*)(hsrc + f * 4);
        }
#pragma unroll
        for (int i = 0; i < 8; i++) {
          const int f = (bb * 8 + i) * NTHR + tx;
          const int r_ = f >> 8;             // local row (256 float4 per row)
          const int c16 = (f & 255) >> 1;    // 16B chunk within row
          const int byte = r_ * 2048 + (((c16 * 16) ^ ((r_ & 7) << 4))) + (f & 1) * 8;
          union { _Float16 h[4]; unsigned long long u; } pk;
          pk.h[0] = (_Float16)d[i].x; pk.h[1] = (_Float16)d[i].y;
          pk.h[2] = (_Float16)d[i].z; pk.h[3] = (_Float16)d[i].w;
          *(unsigned long long*)((char*)hstage + byte) = pk.u;
        }
      }
    }
    __syncthreads();  // sync1: hstage ready

    if (t > 0) {
      // ---- MFMA: wave g computes gates[g][16 rows][32 cols], K=1024 ----
      f32x4 acc0 = {0.f, 0.f, 0.f, 0.f}, acc1 = {0.f, 0.f, 0.f, 0.f};
      const char* hsb = (const char*)hstage;
      const int rbase = cc * 2048;
      const int sw = (cc & 7) << 4;
      half8 bf0[8], bf1[8];
#pragma unroll
      for (int p = 0; p < 8; p++) { bf0[p] = bq0[p * 4]; bf1[p] = bq1[p * 4]; }
#pragma unroll
      for (int ks = 0; ks < 32; ks++) {
        half8 af = *(const half8*)(hsb + rbase + ((ks * 64 + kb2) ^ sw));
        half8 b0 = bf0[ks & 7], b1 = bf1[ks & 7];
        if (ks < 24) { bf0[ks & 7] = bq0[(ks + 8) * 4]; bf1[ks & 7] = bq1[(ks + 8) * 4]; }
        acc0 = __builtin_amdgcn_mfma_f32_16x16x32_f16(af, b0, acc0, 0, 0, 0);
        acc1 = __builtin_amdgcn_mfma_f32_16x16x32_f16(af, b1, acc1, 0, 0, 0);
      }
#pragma unroll
      for (int r = 0; r < 4; r++) {
        gates[g][(l >> 4) * 4 + r][cc]      = acc0[r];
        gates[g][(l >> 4) * 4 + r][16 + cc] = acc1[r];
      }
    } else {
      for (int i = tx; i < 4 * 16 * 36; i += NTHR) ((float*)gates)[i] = 0.f;
    }
    __syncthreads();  // sync2: gates ready

    if (tx < 128) {
      const int rr = tx >> 3, jq = (tx & 7) * 4;
      union { unsigned long long u; _Float16 h[4]; } q0, q1, q2, q3;
      q0.u = gv[0]; q1.u = gv[1]; q2.u = gv[2]; q3.u = gv[3];
      float hv[4];
#pragma unroll
      for (int j = 0; j < 4; j++) {
        const int jj = jq + j;
        float gi = gates[0][rr][jj] + (float)q0.h[j];
        float gf = gates[1][rr][jj] + (float)q1.h[j];
        float gg = gates[2][rr][jj] + (float)q2.h[j];
        float go = gates[3][rr][jj] + (float)q3.h[j];
        float ig = 1.f / (1.f + expf(-gi));
        float fg = 1.f / (1.f + expf(-gf));
        float gvv = tanhf(gg);
        float og = 1.f / (1.f + expf(-go));
        cst[j] = fg * cst[j] + ig * gvv;
        hv[j] = og * tanhf(cst[j]);
        hl[j] = hv[j];
      }
      // h store: proven sc0/sc1 write-through path (2x8B system-scope).
      float* oaddr = out + (size_t)t * (B_SZ * H_SZ) + (size_t)(group * 16 + rr) * H_SZ + jb + jq;
      union { float f[2]; unsigned long long u; } p0, p1;
      p0.f[0] = hv[0]; p0.f[1] = hv[1];
      p1.f[0] = hv[2]; p1.f[1] = hv[3];
      __hip_atomic_store((unsigned long long*)oaddr, p0.u,
                         __ATOMIC_RELAXED, __HIP_MEMORY_SCOPE_SYSTEM);
      __hip_atomic_store((unsigned long long*)oaddr + 1, p1.u,
                         __ATOMIC_RELAXED, __HIP_MEMORY_SCOPE_SYSTEM);
    }

    if (t + 1 < T_SZ) {
      // ---- GROUP-LOCAL flag barrier: 32 WGs, 1 flag line per group ----
      asm volatile("s_waitcnt vmcnt(0)" ::: "memory");  // h stores at LLC
      __syncthreads();                                   // sync3
      if (tx == 0)
        __hip_atomic_store(flags + group * 64 + w, t + 1, __ATOMIC_RELAXED,
                           __HIP_MEMORY_SCOPE_SYSTEM);
      if (g == 0) {
        const int target = t + 1;
        const unsigned long long* fp = (const unsigned long long*)(flags + group * 64);
        int guard = 0;
        for (;;) {
          bool ok = true;
          if (l < 16) {
            unsigned long long f0 = __hip_atomic_load(fp + l, __ATOMIC_RELAXED,
                                                      __HIP_MEMORY_SCOPE_SYSTEM);
            ok = ((int)(f0 & 0xffffffffu) >= target) && ((int)(f0 >> 32) >= target);
          }
          if (__all(ok)) break;
          if (++guard > (1 << 20)) break;  // deadlock -> fast wrong answer
          __builtin_amdgcn_s_sleep(2);
        }
      }
      asm volatile("" ::: "memory");  // no compile-time hoist of stage loads
      __syncthreads();  // sync4
    }
  }

  if (tx < 128) {
    const int rr = tx >> 3, jq = (tx & 7) * 4;
    const size_t ob = (size_t)T_SZ * (B_SZ * H_SZ);
    float* p = out + ob + (size_t)(group * 16 + rr) * H_SZ + jb + jq;
    *(float4*)p = make_float4(hl[0], hl[1], hl[2], hl[3]);
    *(float4*)(p + B_SZ * H_SZ) = make_float4(cst[0], cst[1], cst[2], cst[3]);
  }
}

extern "C" void kernel_launch(void* const* d_in, const int* in_sizes, int n_in,
                              void* d_out, int out_size, void* d_ws, size_t ws_size,
                              hipStream_t stream) {
  (void)in_sizes; (void)n_in; (void)out_size; (void)ws_size;
  const float* x  = (const float*)d_in[0];
  const float* Wi = (const float*)d_in[1];
  const float* Wh = (const float*)d_in[2];
  const float* bi = (const float*)d_in[3];
  const float* bh = (const float*)d_in[4];
  float* out = (float*)d_out;
  char* ws = (char*)d_ws;

  int* ctrl     = (int*)ws;
  _Float16* WhT = (_Float16*)(ws + (size_t)1 * MiB);
  _Float16* WiT = (_Float16*)(ws + (size_t)16 * MiB);
  _Float16* G   = (_Float16*)(ws + (size_t)32 * MiB);

  (void)hipMemsetAsync(ws, 0, 4096, stream);
  k_cvt_wT<<<2048, 256, 0, stream>>>(Wi, WiT);
  k_cvt_wT<<<2048, 256, 0, stream>>>(Wh, WhT);
  dim3 g2(32, 256);
  k_gemm_pre<<<g2, 256, 0, stream>>>(x, WiT, bi, bh, G);
  k_lstm<<<NWG, NTHR, 0, stream>>>(WhT, G, out, ctrl);
}